// Round 4
// baseline (968.503 us; speedup 1.0000x reference)
//
#include <hip/hip_runtime.h>
#include <hip/hip_bf16.h>
#include <stdint.h>

typedef __hip_bfloat16 bf16;
typedef __attribute__((ext_vector_type(8))) short bf16x8;   // 8 bf16 = 4 VGPR
typedef __attribute__((ext_vector_type(4))) float f32x4;
typedef __attribute__((ext_vector_type(4))) int i32x4;

#define B_DIM 4096
#define H_DIM 2048
#define CH1_DIM 256
#define CH2_DIM 128
#define NMEM_DIM 4096

__device__ __forceinline__ float bf2f(bf16 v) { return __bfloat162float(v); }
__device__ __forceinline__ bf16 f2bf(float v) { return __float2bfloat16(v); }

__device__ __forceinline__ float gelu_f(float x) {
  float u = 0.7978845608028654f * (x + 0.044715f * x * x * x);
  float t = 1.0f - 2.0f / (__expf(2.0f * u) + 1.0f);
  return 0.5f * x * (1.0f + t);
}
__device__ __forceinline__ float sigmoid_f(float x) {
  return 1.0f / (1.0f + __expf(-x));
}

__device__ __forceinline__ void async16(const void* g, void* l) {
  __builtin_amdgcn_global_load_lds(
      (const __attribute__((address_space(1))) char*)(uintptr_t)g,
      (__attribute__((address_space(3))) char*)(uintptr_t)l, 16, 0, 0);
}

// unpack ordered-u32 -> float (inverse of the packed-max map)
__device__ __forceinline__ float unord(unsigned ou) {
  return (ou & 0x80000000u) ? __uint_as_float(ou ^ 0x80000000u)
                            : __uint_as_float(~ou);
}

// ---------------------------------------------------------------------------
// dtype probe: flag=1 -> inputs are float32, flag=0 -> bfloat16.
// ---------------------------------------------------------------------------
__global__ void flag_init(int* flag, unsigned* epsku) { *flag = 0; *epsku = 0u; }

__global__ void probe_dtype(const void* x, int* flag) {
  const unsigned short* u = (const unsigned short*)x;
  int i0 = blockIdx.x * 256 + threadIdx.x;
  bool big = false;
#pragma unroll
  for (int k = 0; k < 16; ++k) {
    unsigned short h = u[(size_t)(i0 * 16 + k) * 2];  // even bf16-view index
    unsigned int e = (h >> 7) & 0xFF;
    if (e >= 0x9A) big = true;  // |v| >= 2^27 or inf/nan -> f32 mantissa noise
  }
  if (big) atomicOr(flag, 1);
}

__global__ void ingest(const void* src, bf16* dst, int n, const int* flag) {
  int i = blockIdx.x * 256 + threadIdx.x;
  if (i >= n) return;
  if (*flag) dst[i] = f2bf(((const float*)src)[i]);
  else       dst[i] = ((const bf16*)src)[i];
}

struct SmallJobs { const void* src[9]; bf16* dst[9]; int n[9]; };
__global__ void ingest_small(SmallJobs jobs, const int* flag) {
  int b = blockIdx.x;
  const void* src = jobs.src[b];
  bf16* dst = jobs.dst[b];
  int n = jobs.n[b];
  bool isf = *flag != 0;
  for (int i = threadIdx.x; i < n; i += 256)
    dst[i] = isf ? f2bf(((const float*)src)[i]) : ((const bf16*)src)[i];
}

// ---------------------------------------------------------------------------
// GEMM: C[M,N] = act(A[M,K] @ Bt[N,K]^T + bias). Round-2 verified geometry:
// 16x16x32 bf16 MFMA, quad-based k-groups, XOR row swizzle -> 0 LDS conflicts.
// STAT=1 additionally accumulates per-row sum(v^2) and max|v| (for q stats).
// ---------------------------------------------------------------------------
template <int BT, int ACT, int STAT>
__global__ __launch_bounds__(256, 2) void gemm_bt(
    const bf16* __restrict__ A, const bf16* __restrict__ Bt,
    const bf16* __restrict__ bias, bf16* __restrict__ C,
    float* __restrict__ qsum, unsigned* __restrict__ qamaxu,
    int M, int N, int K, const int* __restrict__ gate) {
  if (gate && *gate == 0) return;
  constexpr int CH = BT / 32;
  constexpr int FR = BT / 32;
  __shared__ __align__(16) bf16 As[BT * 64];
  __shared__ __align__(16) bf16 Bs[BT * 64];

  const int t = threadIdx.x;
  const int lane = t & 63;
  const int wave = t >> 6;
  const int m0 = blockIdx.y * BT;
  const int n0 = blockIdx.x * BT;

  const bf16* gA[CH];
  const bf16* gB[CH];
  int lOff[CH];
#pragma unroll
  for (int p = 0; p < CH; ++p) {
    int c = p * 256 + t;
    int r = c >> 3;
    int g = (c & 7) ^ (r & 7);  // logical k-group stored at this slot
    gA[p] = A + (size_t)(m0 + r) * K + g * 8;
    gB[p] = Bt + (size_t)(n0 + r) * K + g * 8;
    lOff[p] = c * 16;
  }

  f32x4 acc[FR][FR];
#pragma unroll
  for (int i = 0; i < FR; ++i)
#pragma unroll
    for (int j = 0; j < FR; ++j) acc[i][j] = (f32x4){0.f, 0.f, 0.f, 0.f};

  const int wrow = (wave >> 1) * (FR * 16);
  const int wcol = (wave & 1) * (FR * 16);
  const int l15 = lane & 15;
  const int quad = lane >> 4;

  for (int kt = 0; kt < K; kt += 64) {
#pragma unroll
    for (int p = 0; p < CH; ++p) {
      async16(gA[p], (char*)As + lOff[p]);
      async16(gB[p], (char*)Bs + lOff[p]);
      gA[p] += 64;
      gB[p] += 64;
    }
    asm volatile("s_waitcnt vmcnt(0)" ::: "memory");
    __syncthreads();
#pragma unroll
    for (int ks = 0; ks < 2; ++ks) {
      bf16x8 af[FR], bfv[FR];
#pragma unroll
      for (int i = 0; i < FR; ++i) {
        int ra = wrow + i * 16 + l15;
        int g = ks * 4 + quad;
        af[i] = *(const bf16x8*)(As + ra * 64 + ((g ^ (ra & 7)) * 8));
        int rb = wcol + i * 16 + l15;
        bfv[i] = *(const bf16x8*)(Bs + rb * 64 + ((g ^ (rb & 7)) * 8));
      }
#pragma unroll
      for (int i = 0; i < FR; ++i)
#pragma unroll
        for (int j = 0; j < FR; ++j)
          acc[i][j] = __builtin_amdgcn_mfma_f32_16x16x32_bf16(af[i], bfv[j],
                                                              acc[i][j], 0, 0, 0);
    }
    __syncthreads();
  }

  float bv[FR];
#pragma unroll
  for (int j = 0; j < FR; ++j) bv[j] = bf2f(bias[n0 + wcol + j * 16 + l15]);

#pragma unroll
  for (int i = 0; i < FR; ++i) {
#pragma unroll
    for (int r = 0; r < 4; ++r) {
      int row = m0 + wrow + i * 16 + quad * 4 + r;
      float ss = 0.f, am = 0.f;
#pragma unroll
      for (int j = 0; j < FR; ++j) {
        int col = n0 + wcol + j * 16 + l15;
        float v = acc[i][j][r] + bv[j];
        if (ACT == 1) v = gelu_f(v);
        C[(size_t)row * N + col] = f2bf(v);
        if (STAT) { ss += v * v; am = fmaxf(am, fabsf(v)); }
      }
      if (STAT) {
#pragma unroll
        for (int m = 1; m < 16; m <<= 1) {
          ss += __shfl_xor(ss, m, 64);
          am = fmaxf(am, __shfl_xor(am, m, 64));
        }
        if (l15 == 0) {
          atomicAdd(qsum + row, ss);
          atomicMax(qamaxu + row, __float_as_uint(am));
        }
      }
    }
  }
}

// ---------------------------------------------------------------------------
// int8 sim GEMM: acc = qi8 @ ki8^T (i32), epilogue scales to approx cosine*usage
// and packed-max-reduces per row. BK=128 i8 bytes -> byte-identical LDS
// geometry to the verified bf16 tile (128B rows, 8x16B groups, quad k-groups).
// ---------------------------------------------------------------------------
__global__ __launch_bounds__(256, 2) void gemm_sim_i8(
    const char* __restrict__ Qi, const char* __restrict__ Ki,
    const float* __restrict__ qscale, const float* __restrict__ kscale,
    unsigned long long* __restrict__ amax, int M, int N, int K,
    const int* __restrict__ gate) {
  if (*gate == 0) return;
  __shared__ __align__(16) char As[128 * 128];
  __shared__ __align__(16) char Bs[128 * 128];

  const int t = threadIdx.x;
  const int lane = t & 63;
  const int wave = t >> 6;
  const int m0 = blockIdx.y * 128;
  const int n0 = blockIdx.x * 128;
  const int l15 = lane & 15;
  const int quad = lane >> 4;
  const int wrow = (wave >> 1) * 64;
  const int wcol = (wave & 1) * 64;

  const char* gA[4];
  const char* gB[4];
  int lOff[4];
#pragma unroll
  for (int p = 0; p < 4; ++p) {
    int c = p * 256 + t;
    int r = c >> 3;
    int g = (c & 7) ^ (r & 7);
    gA[p] = Qi + (size_t)(m0 + r) * K + g * 16;
    gB[p] = Ki + (size_t)(n0 + r) * K + g * 16;
    lOff[p] = c * 16;
  }

  i32x4 acc[4][4];
#pragma unroll
  for (int i = 0; i < 4; ++i)
#pragma unroll
    for (int j = 0; j < 4; ++j) acc[i][j] = (i32x4){0, 0, 0, 0};

  for (int kt = 0; kt < K; kt += 128) {
#pragma unroll
    for (int p = 0; p < 4; ++p) {
      async16(gA[p], As + lOff[p]);
      async16(gB[p], Bs + lOff[p]);
      gA[p] += 128;
      gB[p] += 128;
    }
    asm volatile("s_waitcnt vmcnt(0)" ::: "memory");
    __syncthreads();
#pragma unroll
    for (int ks = 0; ks < 2; ++ks) {
      int g = ks * 4 + quad;
      i32x4 af[4], bfv[4];
#pragma unroll
      for (int i = 0; i < 4; ++i) {
        int ra = wrow + i * 16 + l15;
        af[i] = *(const i32x4*)(As + ra * 128 + ((g ^ (ra & 7)) * 16));
        int rb = wcol + i * 16 + l15;
        bfv[i] = *(const i32x4*)(Bs + rb * 128 + ((g ^ (rb & 7)) * 16));
      }
#pragma unroll
      for (int i = 0; i < 4; ++i)
#pragma unroll
        for (int j = 0; j < 4; ++j)
          acc[i][j] = __builtin_amdgcn_mfma_i32_16x16x64_i8(af[i], bfv[j],
                                                            acc[i][j], 0, 0, 0);
    }
    __syncthreads();
  }

  float ksc[4];
#pragma unroll
  for (int j = 0; j < 4; ++j) ksc[j] = kscale[n0 + wcol + j * 16 + l15];

#pragma unroll
  for (int i = 0; i < 4; ++i) {
#pragma unroll
    for (int r = 0; r < 4; ++r) {
      int row = m0 + wrow + i * 16 + quad * 4 + r;
      float qs = qscale[row];
      float best = -1e30f;
      int bidx = 0;
#pragma unroll
      for (int j = 0; j < 4; ++j) {
        int col = n0 + wcol + j * 16 + l15;
        float v = (float)acc[i][j][r] * qs * ksc[j];
        if (v > best) { best = v; bidx = col; }
      }
      unsigned int u = __float_as_uint(best);
      unsigned int ou = (u & 0x80000000u) ? ~u : (u | 0x80000000u);
      unsigned long long pk =
          ((unsigned long long)ou << 32) |
          (unsigned long long)(0xFFFFFFFFu - (unsigned int)bidx);
#pragma unroll
      for (int m = 1; m < 16; m <<= 1) {
        unsigned long long o = (unsigned long long)__shfl_xor((long long)pk, m, 64);
        if (o > pk) pk = o;
      }
      if (l15 == 0) atomicMax(amax + row, pk);
    }
  }
}

// --- small kernels ---------------------------------------------------------

__global__ void transpose_any(const void* __restrict__ src, bf16* __restrict__ dst,
                              int R, int C, const int* __restrict__ flag) {
  __shared__ bf16 tile[64][65];
  const int isf = *flag;
  int c0 = blockIdx.x * 64, r0 = blockIdx.y * 64;
#pragma unroll 4
  for (int p = 0; p < 16; ++p) {
    int idx = p * 256 + threadIdx.x;
    int r = idx >> 6, c = idx & 63;
    size_t si = (size_t)(r0 + r) * C + (c0 + c);
    tile[r][c] = isf ? f2bf(((const float*)src)[si]) : ((const bf16*)src)[si];
  }
  __syncthreads();
#pragma unroll 4
  for (int p = 0; p < 16; ++p) {
    int idx = p * 256 + threadIdx.x;
    int r = idx >> 6, c = idx & 63;
    dst[(size_t)(c0 + r) * R + (r0 + c)] = tile[c][r];
  }
}

// per-key: quantize to i8, scales for i8 sim + exact fallback, global eps_k max
__global__ void quant_keys(const bf16* __restrict__ keysb,
                           const void* __restrict__ usage,
                           char* __restrict__ Ki, float* __restrict__ kscale_i8,
                           float* __restrict__ kscale_e, unsigned* __restrict__ epsku,
                           int cols, const int* __restrict__ flag) {
  int row = blockIdx.x;
  const bf16* xr = keysb + (size_t)row * cols;
  float ss = 0.f, am = 0.f;
  for (int i = threadIdx.x * 8; i < cols; i += 256 * 8) {
    union { uint4 u; bf16 h[8]; } u;
    u.u = *(const uint4*)(xr + i);
#pragma unroll
    for (int j = 0; j < 8; ++j) {
      float f = bf2f(u.h[j]);
      ss += f * f;
      am = fmaxf(am, fabsf(f));
    }
  }
  __shared__ float rs[256], ra[256];
  rs[threadIdx.x] = ss; ra[threadIdx.x] = am;
  __syncthreads();
  for (int k = 128; k > 0; k >>= 1) {
    if (threadIdx.x < k) {
      rs[threadIdx.x] += rs[threadIdx.x + k];
      ra[threadIdx.x] = fmaxf(ra[threadIdx.x], ra[threadIdx.x + k]);
    }
    __syncthreads();
  }
  float nrm = fmaxf(sqrtf(rs[0]), 1e-8f);
  float kam = ra[0];
  if (threadIdx.x == 0) {
    float us = *flag ? ((const float*)usage)[row] : bf2f(((const bf16*)usage)[row]);
    kscale_e[row] = us / nrm;
    kscale_i8[row] = us * kam / (127.f * nrm);
    float eps = fabsf(us) * sqrtf((float)cols) * kam / (254.f * nrm);
    atomicMax(epsku, __float_as_uint(eps));
  }
  float inv = (kam > 0.f) ? 127.f / kam : 0.f;
  char* dr = Ki + (size_t)row * cols;
  for (int i = threadIdx.x * 8; i < cols; i += 256 * 8) {
    union { uint4 u; bf16 h[8]; } u;
    u.u = *(const uint4*)(xr + i);
    union { uint2 w; char c[8]; } o;
#pragma unroll
    for (int j = 0; j < 8; ++j) {
      int v = __float2int_rn(bf2f(u.h[j]) * inv);
      o.c[j] = (char)max(-127, min(127, v));
    }
    *(uint2*)(dr + i) = o.w;
  }
}

// per-row quantize q to i8 using folded stats (qsum, qamax) from mq epilogue
__global__ void quant_q(const bf16* __restrict__ q, const float* __restrict__ qsum,
                        const unsigned* __restrict__ qamaxu, char* __restrict__ Qi,
                        float* __restrict__ qscale, int cols,
                        const int* __restrict__ gate) {
  if (*gate == 0) return;
  int row = blockIdx.x;
  float am = __uint_as_float(qamaxu[row]);
  float nrm = fmaxf(sqrtf(qsum[row]), 1e-8f);
  if (threadIdx.x == 0) qscale[row] = am / (127.f * nrm);
  float inv = (am > 0.f) ? 127.f / am : 0.f;
  const bf16* xr = q + (size_t)row * cols;
  char* dr = Qi + (size_t)row * cols;
  for (int i = threadIdx.x * 8; i < cols; i += 256 * 8) {
    union { uint4 u; bf16 h[8]; } u;
    u.u = *(const uint4*)(xr + i);
    union { uint2 w; char c[8]; } o;
#pragma unroll
    for (int j = 0; j < 8; ++j) {
      int v = __float2int_rn(bf2f(u.h[j]) * inv);
      o.c[j] = (char)max(-127, min(127, v));
    }
    *(uint2*)(dr + i) = o.w;
  }
}

// certify rows: if approx max + quantization slack could cross 0.9, flag for
// exact recompute. (Never fires for gaussian data: max cos ~0.09, slack ~0.05.)
__global__ void check_rows(const unsigned long long* __restrict__ amax,
                           const float* __restrict__ qsum,
                           const unsigned* __restrict__ qamaxu,
                           const unsigned* __restrict__ epsku,
                           int* __restrict__ rowflag, int* __restrict__ gflag,
                           int n, int cols, const int* __restrict__ gate) {
  if (*gate == 0) return;
  int i = blockIdx.x * 256 + threadIdx.x;
  if (i >= n) return;
  float val = unord((unsigned)(amax[i] >> 32));
  float am = __uint_as_float(qamaxu[i]);
  float nrm = fmaxf(sqrtf(qsum[i]), 1e-8f);
  float epsq = sqrtf((float)cols) * am / (254.f * nrm);
  float epsk = __uint_as_float(*epsku);
  float slack = epsq + epsk + epsq * epsk + 0.02f;
  if (val + slack > 0.9f) { rowflag[i] = 1; atomicOr(gflag, 1); }
}

// exact bf16 fallback for flagged rows (writes exact packed (sim,idx))
__global__ void sim_exact_row(const bf16* __restrict__ q,
                              const bf16* __restrict__ keysb,
                              const float* __restrict__ qsum,
                              const float* __restrict__ kscale_e,
                              const int* __restrict__ rowflag,
                              const int* __restrict__ gflag,
                              unsigned long long* __restrict__ amax,
                              int cols, int nkeys, const int* __restrict__ gate) {
  if (*gate == 0 || *gflag == 0) return;
  int b = blockIdx.x;
  if (!rowflag[b]) return;
  float qinv = rsqrtf(fmaxf(qsum[b], 1e-16f));
  const bf16* qr = q + (size_t)b * cols;
  unsigned long long best = 0ull;
  for (int c = threadIdx.x; c < nkeys; c += 256) {
    const bf16* kr = keysb + (size_t)c * cols;
    float dot = 0.f;
    for (int k = 0; k < cols; k += 8) {
      union { uint4 u; bf16 h[8]; } a, bb;
      a.u = *(const uint4*)(qr + k);
      bb.u = *(const uint4*)(kr + k);
#pragma unroll
      for (int j = 0; j < 8; ++j) dot += bf2f(a.h[j]) * bf2f(bb.h[j]);
    }
    float sim = dot * qinv * kscale_e[c];
    unsigned u = __float_as_uint(sim);
    unsigned ou = (u & 0x80000000u) ? ~u : (u | 0x80000000u);
    unsigned long long pk = ((unsigned long long)ou << 32) |
                            (unsigned long long)(0xFFFFFFFFu - (unsigned)c);
    if (pk > best) best = pk;
  }
  __shared__ unsigned long long red[256];
  red[threadIdx.x] = best;
  __syncthreads();
  for (int k = 128; k > 0; k >>= 1) {
    if (threadIdx.x < k)
      red[threadIdx.x] = red[threadIdx.x] > red[threadIdx.x + k]
                             ? red[threadIdx.x] : red[threadIdx.x + k];
    __syncthreads();
  }
  if (threadIdx.x == 0) amax[b] = red[0];
}

__global__ void conf_head(const bf16* __restrict__ h2, const bf16* __restrict__ w3,
                          const bf16* __restrict__ b3, const bf16* __restrict__ slope,
                          const bf16* __restrict__ cbias, float* __restrict__ conf,
                          const int* __restrict__ gate) {
  if (gate && *gate == 0) return;
  int wave = threadIdx.x >> 6, lane = threadIdx.x & 63;
  int row = blockIdx.x * 4 + wave;
  const bf16* hr = h2 + (size_t)row * CH2_DIM;
  float s = bf2f(hr[lane]) * bf2f(w3[lane]) +
            bf2f(hr[lane + 64]) * bf2f(w3[lane + 64]);
  for (int m = 32; m > 0; m >>= 1) s += __shfl_xor(s, m, 64);
  if (lane == 0) {
    float raw = sigmoid_f(s + bf2f(b3[0]));
    conf[row] = sigmoid_f(bf2f(slope[0]) * (raw - 0.5f) + bf2f(cbias[0]));
  }
}

__global__ void reduce_conf(const float* __restrict__ conf, float* __restrict__ cmean,
                            int n, const int* __restrict__ gate) {
  if (gate && *gate == 0) return;
  __shared__ float red[256];
  float s = 0.f;
  for (int i = threadIdx.x; i < n; i += 256) s += conf[i];
  red[threadIdx.x] = s;
  __syncthreads();
  for (int k = 128; k > 0; k >>= 1) {
    if (threadIdx.x < k) red[threadIdx.x] += red[threadIdx.x + k];
    __syncthreads();
  }
  if (threadIdx.x == 0) *cmean = red[0] / (float)n;
}

// ctrl: [0]=adaptive_max_depth, [1]=depth, [2]=stopped, [3..7]=do_compute[d]
__global__ void init_control(const float* __restrict__ cmean, int* __restrict__ ctrl) {
  float cf = 1.0f - *cmean;
  int amd = 1 + (int)(cf * 4.0f);
  if (amd > 5) amd = 5;
  ctrl[0] = amd;
  ctrl[1] = 0;
  ctrl[2] = 0;
}

__global__ void step_control(const float* __restrict__ cmean, int* __restrict__ ctrl,
                             int d) {
  int amd = ctrl[0], depth = ctrl[1], stopped = ctrl[2];
  bool brk = (*cmean >= 0.85f);
  bool active = (!stopped) && (d < amd);
  if (active) depth = d + 1;
  ctrl[3 + d] = (active && !brk) ? 1 : 0;
  if (active && brk) stopped = 1;
  ctrl[1] = depth;
  ctrl[2] = stopped;
}

__global__ void init_lookup(unsigned long long* __restrict__ amax,
                            float* __restrict__ qsum, unsigned* __restrict__ qamaxu,
                            int* __restrict__ rowflag, int* __restrict__ gflag,
                            int n, const int* __restrict__ gate) {
  if (*gate == 0) return;
  int i = blockIdx.x * 256 + threadIdx.x;
  if (i < n) { amax[i] = 0ull; qsum[i] = 0.f; qamaxu[i] = 0u; rowflag[i] = 0; }
  if (i == 0) *gflag = 0;
}

// in-place: replace S row with mem_values row only when best_sim > 0.9
__global__ void select_mem(const unsigned long long* __restrict__ amax,
                           const void* __restrict__ mv, bf16* __restrict__ S,
                           int Hc, const int* __restrict__ gate,
                           const int* __restrict__ flag) {
  if (gate && *gate == 0) return;
  int b = blockIdx.x;
  unsigned long long pk = amax[b];
  unsigned int ou = (unsigned int)(pk >> 32);
  if (!(ou > 0xBF666666u)) return;  // ordered(0.9f); strict >
  int idx = (int)(0xFFFFFFFFu - (unsigned int)(pk & 0xFFFFFFFFull));
  bf16* dst = S + (size_t)b * Hc;
  if (*flag) {
    const float* src = (const float*)mv + (size_t)idx * Hc;
    for (int i = threadIdx.x; i < Hc; i += 256) dst[i] = f2bf(src[i]);
  } else {
    const uint4* src = (const uint4*)((const bf16*)mv + (size_t)idx * Hc);
    for (int i = threadIdx.x; i < Hc / 8; i += 256) ((uint4*)dst)[i] = src[i];
  }
}

__global__ void emit_state(const bf16* __restrict__ S, void* __restrict__ out,
                           int n, const int* __restrict__ flag) {
  int i = blockIdx.x * 256 + threadIdx.x;
  if (i >= n) return;
  if (*flag) ((float*)out)[i] = bf2f(S[i]);
  else       ((bf16*)out)[i] = S[i];
}

__global__ void write_tail(const float* __restrict__ conf, const int* __restrict__ ctrl,
                           void* __restrict__ out, int bh, int n,
                           const int* __restrict__ flag) {
  int i = blockIdx.x * 256 + threadIdx.x;
  if (i >= n) return;
  if (*flag) {
    ((float*)out)[bh + 1 + i] = conf[i];
    if (i == 0) ((float*)out)[bh] = (float)ctrl[1];
  } else {
    ((bf16*)out)[bh + 1 + i] = f2bf(conf[i]);
    if (i == 0) ((bf16*)out)[bh] = f2bf((float)ctrl[1]);
  }
}

// ---------------------------------------------------------------------------

extern "C" void kernel_launch(void* const* d_in, const int* in_sizes, int n_in,
                              void* d_out, int out_size, void* d_ws, size_t ws_size,
                              hipStream_t stream) {
  const int B = B_DIM, H = H_DIM, H2 = 2 * H_DIM, C1 = CH1_DIM, C2 = CH2_DIM,
            NM = NMEM_DIM;
  const void* x = d_in[0];
  const void* cw1 = d_in[1];
  const void* cb1 = d_in[2];
  const void* cw2 = d_in[3];
  const void* cb2 = d_in[4];
  const void* cw3 = d_in[5];
  const void* cb3 = d_in[6];
  const void* cal_slope = d_in[7];
  const void* cal_bias = d_in[8];
  const void* rw1 = d_in[9];
  const void* rb1 = d_in[10];
  const void* rw2 = d_in[11];
  const void* rb2 = d_in[12];
  const void* mqw = d_in[13];
  const void* mqb = d_in[14];
  const void* mem_keys = d_in[15];
  const void* mem_values = d_in[16];
  const void* mem_usage = d_in[17];

  char* ws = (char*)d_ws;
  size_t off = 0;
  auto alloc = [&](size_t bytes) -> char* {
    char* p = ws + off;
    off = (off + bytes + 255) & ~(size_t)255;
    return p;
  };
  bf16* rw1t = (bf16*)alloc((size_t)H2 * H * 2);
  bf16* rw2t = (bf16*)alloc((size_t)H * H2 * 2);
  bf16* mqwt = (bf16*)alloc((size_t)H * H * 2);
  bf16* cw1t = (bf16*)alloc((size_t)C1 * H * 2);
  bf16* cw2t = (bf16*)alloc((size_t)C2 * C1 * 2);
  bf16* keysb = (bf16*)alloc((size_t)NM * H * 2);
  char* ki8 = (char*)alloc((size_t)NM * H);
  bf16* S = (bf16*)alloc((size_t)B * H * 2);
  bf16* Hbuf = (bf16*)alloc((size_t)B * H2 * 2);
  bf16* q = Hbuf;                               // q aliases lower half of Hbuf
  char* qi8 = (char*)(Hbuf + (size_t)B * H);    // qi8 aliases upper half
  bf16* h1 = (bf16*)alloc((size_t)B * C1 * 2);
  bf16* h2 = (bf16*)alloc((size_t)B * C2 * 2);
  bf16* rb1b = (bf16*)alloc((size_t)H2 * 2);
  bf16* rb2b = (bf16*)alloc((size_t)H * 2);
  bf16* mqbb = (bf16*)alloc((size_t)H * 2);
  bf16* cb1b = (bf16*)alloc((size_t)C1 * 2);
  bf16* cb2b = (bf16*)alloc((size_t)C2 * 2);
  bf16* cw3b = (bf16*)alloc((size_t)C2 * 2);
  bf16* cb3b = (bf16*)alloc(256);
  bf16* slopeb = (bf16*)alloc(256);
  bf16* cbiasb = (bf16*)alloc(256);
  float* conf = (float*)alloc((size_t)B * 4);
  float* qsum = (float*)alloc((size_t)B * 4);
  unsigned* qamaxu = (unsigned*)alloc((size_t)B * 4);
  float* qscale = (float*)alloc((size_t)B * 4);
  float* kscale_i8 = (float*)alloc((size_t)NM * 4);
  float* kscale_e = (float*)alloc((size_t)NM * 4);
  int* rowflag = (int*)alloc((size_t)B * 4);
  unsigned long long* amax = (unsigned long long*)alloc((size_t)B * 8);
  float* cmean = (float*)alloc(256);
  int* ctrl = (int*)alloc(256);
  int* dflag = (int*)alloc(256);
  unsigned* epsku = (unsigned*)alloc(256);
  int* gflag = (int*)alloc(256);
  (void)ws_size; (void)n_in; (void)in_sizes; (void)out_size;

  dim3 blk(256);

  // --- dtype probe ---
  flag_init<<<1, 1, 0, stream>>>(dflag, epsku);
  probe_dtype<<<64, blk, 0, stream>>>(x, dflag);

  // --- ingest to bf16 ---
  ingest<<<(B * H + 255) / 256, blk, 0, stream>>>(x, S, B * H, dflag);
  ingest<<<(NM * H + 255) / 256, blk, 0, stream>>>(mem_keys, keysb, NM * H, dflag);
  SmallJobs sj;
  sj.src[0] = rb1;       sj.dst[0] = rb1b;   sj.n[0] = H2;
  sj.src[1] = rb2;       sj.dst[1] = rb2b;   sj.n[1] = H;
  sj.src[2] = mqb;       sj.dst[2] = mqbb;   sj.n[2] = H;
  sj.src[3] = cb1;       sj.dst[3] = cb1b;   sj.n[3] = C1;
  sj.src[4] = cb2;       sj.dst[4] = cb2b;   sj.n[4] = C2;
  sj.src[5] = cw3;       sj.dst[5] = cw3b;   sj.n[5] = C2;
  sj.src[6] = cb3;       sj.dst[6] = cb3b;   sj.n[6] = 1;
  sj.src[7] = cal_slope; sj.dst[7] = slopeb; sj.n[7] = 1;
  sj.src[8] = cal_bias;  sj.dst[8] = cbiasb; sj.n[8] = 1;
  ingest_small<<<9, blk, 0, stream>>>(sj, dflag);

  // --- weight transposes (B^T form) + key quantization ---
  transpose_any<<<dim3(H2 / 64, H / 64), blk, 0, stream>>>(rw1, rw1t, H, H2, dflag);
  transpose_any<<<dim3(H / 64, H2 / 64), blk, 0, stream>>>(rw2, rw2t, H2, H, dflag);
  transpose_any<<<dim3(H / 64, H / 64), blk, 0, stream>>>(mqw, mqwt, H, H, dflag);
  transpose_any<<<dim3(C1 / 64, H / 64), blk, 0, stream>>>(cw1, cw1t, H, C1, dflag);
  transpose_any<<<dim3(C2 / 64, C1 / 64), blk, 0, stream>>>(cw2, cw2t, C1, C2, dflag);
  quant_keys<<<NM, blk, 0, stream>>>(keysb, mem_usage, ki8, kscale_i8, kscale_e,
                                     epsku, H, dflag);

  auto conf_pipe = [&](const bf16* Sin, const int* gate) {
    gemm_bt<64, 1, 0><<<dim3(C1 / 64, B / 64), blk, 0, stream>>>(
        Sin, cw1t, cb1b, h1, nullptr, nullptr, B, C1, H, gate);
    gemm_bt<64, 1, 0><<<dim3(C2 / 64, B / 64), blk, 0, stream>>>(
        h1, cw2t, cb2b, h2, nullptr, nullptr, B, C2, C1, gate);
    conf_head<<<B / 4, blk, 0, stream>>>(h2, cw3b, cb3b, slopeb, cbiasb, conf, gate);
    reduce_conf<<<1, blk, 0, stream>>>(conf, cmean, B, gate);
  };

  conf_pipe(S, nullptr);
  init_control<<<1, 1, 0, stream>>>(cmean, ctrl);

  for (int d = 0; d < 5; ++d) {
    step_control<<<1, 1, 0, stream>>>(cmean, ctrl, d);
    const int* gate = ctrl + 3 + d;
    if (d >= 1) {
      init_lookup<<<B / 256, blk, 0, stream>>>(amax, qsum, qamaxu, rowflag, gflag,
                                               B, gate);
      gemm_bt<128, 0, 1><<<dim3(H / 128, B / 128), blk, 0, stream>>>(
          S, mqwt, mqbb, q, qsum, qamaxu, B, H, H, gate);
      quant_q<<<B, blk, 0, stream>>>(q, qsum, qamaxu, qi8, qscale, H, gate);
      gemm_sim_i8<<<dim3(NM / 128, B / 128), blk, 0, stream>>>(
          qi8, ki8, qscale, kscale_i8, amax, B, NM, H, gate);
      check_rows<<<B / 256, blk, 0, stream>>>(amax, qsum, qamaxu, epsku, rowflag,
                                              gflag, B, H, gate);
      sim_exact_row<<<B, blk, 0, stream>>>(q, keysb, qsum, kscale_e, rowflag,
                                           gflag, amax, H, NM, gate);
      select_mem<<<B, blk, 0, stream>>>(amax, mem_values, S, H, gate, dflag);
    }
    gemm_bt<128, 1, 0><<<dim3(H2 / 128, B / 128), blk, 0, stream>>>(
        S, rw1t, rb1b, Hbuf, nullptr, nullptr, B, H2, H, gate);
    gemm_bt<128, 0, 0><<<dim3(H / 128, B / 128), blk, 0, stream>>>(
        Hbuf, rw2t, rb2b, S, nullptr, nullptr, B, H, H2, gate);
    conf_pipe(S, gate);
  }

  emit_state<<<(B * H + 255) / 256, blk, 0, stream>>>(S, d_out, B * H, dflag);
  write_tail<<<B / 256, blk, 0, stream>>>(conf, ctrl, d_out, B * H, B, dflag);
}

// Round 5
// 909.786 us; speedup vs baseline: 1.0645x; 1.0645x over previous
//
#include <hip/hip_runtime.h>
#include <hip/hip_bf16.h>
#include <stdint.h>

typedef __hip_bfloat16 bf16;
typedef __attribute__((ext_vector_type(8))) short bf16x8;   // 8 bf16 = 4 VGPR
typedef __attribute__((ext_vector_type(4))) float f32x4;

#define B_DIM 4096
#define H_DIM 2048
#define CH1_DIM 256
#define CH2_DIM 128
#define NMEM_DIM 4096

__device__ __forceinline__ float bf2f(bf16 v) { return __bfloat162float(v); }
__device__ __forceinline__ bf16 f2bf(float v) { return __float2bfloat16(v); }

__device__ __forceinline__ float gelu_f(float x) {
  float u = 0.7978845608028654f * (x + 0.044715f * x * x * x);
  float t = 1.0f - 2.0f / (__expf(2.0f * u) + 1.0f);
  return 0.5f * x * (1.0f + t);
}
__device__ __forceinline__ float sigmoid_f(float x) {
  return 1.0f / (1.0f + __expf(-x));
}

__device__ __forceinline__ void async16(const void* g, void* l) {
  __builtin_amdgcn_global_load_lds(
      (const __attribute__((address_space(1))) char*)(uintptr_t)g,
      (__attribute__((address_space(3))) char*)(uintptr_t)l, 16, 0, 0);
}

// ---------------------------------------------------------------------------
// dtype probe: flag=1 -> inputs are float32, flag=0 -> bfloat16.
// ---------------------------------------------------------------------------
__global__ void flag_init(int* flag) { *flag = 0; }

__global__ void probe_dtype(const void* x, int* flag) {
  const unsigned short* u = (const unsigned short*)x;
  int i0 = blockIdx.x * 256 + threadIdx.x;
  bool big = false;
#pragma unroll
  for (int k = 0; k < 16; ++k) {
    unsigned short h = u[(size_t)(i0 * 16 + k) * 2];  // even bf16-view index
    unsigned int e = (h >> 7) & 0xFF;
    if (e >= 0x9A) big = true;  // |v| >= 2^27 or inf/nan -> f32 mantissa noise
  }
  if (big) atomicOr(flag, 1);
}

__global__ void ingest(const void* src, bf16* dst, int n, const int* flag) {
  int i = blockIdx.x * 256 + threadIdx.x;
  if (i >= n) return;
  if (*flag) dst[i] = f2bf(((const float*)src)[i]);
  else       dst[i] = ((const bf16*)src)[i];
}

struct SmallJobs { const void* src[9]; bf16* dst[9]; int n[9]; };
__global__ void ingest_small(SmallJobs jobs, const int* flag) {
  int b = blockIdx.x;
  const void* src = jobs.src[b];
  bf16* dst = jobs.dst[b];
  int n = jobs.n[b];
  bool isf = *flag != 0;
  for (int i = threadIdx.x; i < n; i += 256)
    dst[i] = isf ? f2bf(((const float*)src)[i]) : ((const bf16*)src)[i];
}

// ---------------------------------------------------------------------------
// GEMM: C[M,N] = act(A[M,K] @ Bt[N,K]^T + bias). Round-2 verified geometry:
// 16x16x32 bf16 MFMA, quad-based k-groups, XOR row swizzle -> 0 LDS conflicts
// (measured). STAT=1 additionally folds per-row sum(v^2) into qsum.
// ---------------------------------------------------------------------------
template <int BT, int ACT, int STAT>
__global__ __launch_bounds__(256, 2) void gemm_bt(
    const bf16* __restrict__ A, const bf16* __restrict__ Bt,
    const bf16* __restrict__ bias, bf16* __restrict__ C,
    float* __restrict__ qsum, int M, int N, int K,
    const int* __restrict__ gate) {
  if (gate && *gate == 0) return;
  constexpr int CH = BT / 32;
  constexpr int FR = BT / 32;
  __shared__ __align__(16) bf16 As[BT * 64];
  __shared__ __align__(16) bf16 Bs[BT * 64];

  const int t = threadIdx.x;
  const int lane = t & 63;
  const int wave = t >> 6;
  const int m0 = blockIdx.y * BT;
  const int n0 = blockIdx.x * BT;

  const bf16* gA[CH];
  const bf16* gB[CH];
  int lOff[CH];
#pragma unroll
  for (int p = 0; p < CH; ++p) {
    int c = p * 256 + t;
    int r = c >> 3;
    int g = (c & 7) ^ (r & 7);  // logical k-group stored at this slot
    gA[p] = A + (size_t)(m0 + r) * K + g * 8;
    gB[p] = Bt + (size_t)(n0 + r) * K + g * 8;
    lOff[p] = c * 16;
  }

  f32x4 acc[FR][FR];
#pragma unroll
  for (int i = 0; i < FR; ++i)
#pragma unroll
    for (int j = 0; j < FR; ++j) acc[i][j] = (f32x4){0.f, 0.f, 0.f, 0.f};

  const int wrow = (wave >> 1) * (FR * 16);
  const int wcol = (wave & 1) * (FR * 16);
  const int l15 = lane & 15;
  const int quad = lane >> 4;

  for (int kt = 0; kt < K; kt += 64) {
#pragma unroll
    for (int p = 0; p < CH; ++p) {
      async16(gA[p], (char*)As + lOff[p]);
      async16(gB[p], (char*)Bs + lOff[p]);
      gA[p] += 64;
      gB[p] += 64;
    }
    asm volatile("s_waitcnt vmcnt(0)" ::: "memory");
    __syncthreads();
#pragma unroll
    for (int ks = 0; ks < 2; ++ks) {
      bf16x8 af[FR], bfv[FR];
#pragma unroll
      for (int i = 0; i < FR; ++i) {
        int ra = wrow + i * 16 + l15;
        int g = ks * 4 + quad;
        af[i] = *(const bf16x8*)(As + ra * 64 + ((g ^ (ra & 7)) * 8));
        int rb = wcol + i * 16 + l15;
        bfv[i] = *(const bf16x8*)(Bs + rb * 64 + ((g ^ (rb & 7)) * 8));
      }
#pragma unroll
      for (int i = 0; i < FR; ++i)
#pragma unroll
        for (int j = 0; j < FR; ++j)
          acc[i][j] = __builtin_amdgcn_mfma_f32_16x16x32_bf16(af[i], bfv[j],
                                                              acc[i][j], 0, 0, 0);
    }
    __syncthreads();
  }

  if constexpr (STAT == 0) {
    // Round-2 exact epilogue order (measured 79.3 us on the big tiles)
#pragma unroll
    for (int j = 0; j < FR; ++j) {
      int col = n0 + wcol + j * 16 + l15;
      float bv = bf2f(bias[col]);
#pragma unroll
      for (int i = 0; i < FR; ++i) {
#pragma unroll
        for (int r = 0; r < 4; ++r) {
          int row = m0 + wrow + i * 16 + quad * 4 + r;
          float v = acc[i][j][r] + bv;
          if (ACT == 1) v = gelu_f(v);
          C[(size_t)row * N + col] = f2bf(v);
        }
      }
    }
  } else {
    float bv[FR];
#pragma unroll
    for (int j = 0; j < FR; ++j) bv[j] = bf2f(bias[n0 + wcol + j * 16 + l15]);
#pragma unroll
    for (int i = 0; i < FR; ++i) {
#pragma unroll
      for (int r = 0; r < 4; ++r) {
        int row = m0 + wrow + i * 16 + quad * 4 + r;
        float ss = 0.f;
#pragma unroll
        for (int j = 0; j < FR; ++j) {
          int col = n0 + wcol + j * 16 + l15;
          float v = acc[i][j][r] + bv[j];
          if (ACT == 1) v = gelu_f(v);
          C[(size_t)row * N + col] = f2bf(v);
          ss += v * v;
        }
#pragma unroll
        for (int m = 1; m < 16; m <<= 1) ss += __shfl_xor(ss, m, 64);
        if (l15 == 0) atomicAdd(qsum + row, ss);
      }
    }
  }
}

// ---------------------------------------------------------------------------
// sim GEMM (Round-2 verified, 0 conflicts): acc = q @ keys^T; epilogue scales
// by rsqrt(qsum[row]) * kscale[col], packed-max-reduces per row via u64
// atomicMax (hi=ordered float, lo=~idx -> first-occurrence tie-break).
// ---------------------------------------------------------------------------
__global__ __launch_bounds__(256, 2) void gemm_sim(
    const bf16* __restrict__ Q, const bf16* __restrict__ Kb,
    const float* __restrict__ qsum, const float* __restrict__ kscale,
    unsigned long long* __restrict__ amax, int M, int N, int K,
    const int* __restrict__ gate) {
  if (*gate == 0) return;
  __shared__ __align__(16) bf16 As[128 * 64];
  __shared__ __align__(16) bf16 Bs[128 * 64];

  const int t = threadIdx.x;
  const int lane = t & 63;
  const int wave = t >> 6;
  const int m0 = blockIdx.y * 128;
  const int n0 = blockIdx.x * 128;

  const bf16* gA[4];
  const bf16* gB[4];
  int lOff[4];
#pragma unroll
  for (int p = 0; p < 4; ++p) {
    int c = p * 256 + t;
    int r = c >> 3;
    int g = (c & 7) ^ (r & 7);
    gA[p] = Q + (size_t)(m0 + r) * K + g * 8;
    gB[p] = Kb + (size_t)(n0 + r) * K + g * 8;
    lOff[p] = c * 16;
  }

  f32x4 acc[4][4];
#pragma unroll
  for (int i = 0; i < 4; ++i)
#pragma unroll
    for (int j = 0; j < 4; ++j) acc[i][j] = (f32x4){0.f, 0.f, 0.f, 0.f};

  const int wrow = (wave >> 1) * 64;
  const int wcol = (wave & 1) * 64;
  const int l15 = lane & 15;
  const int quad = lane >> 4;

  for (int kt = 0; kt < K; kt += 64) {
#pragma unroll
    for (int p = 0; p < 4; ++p) {
      async16(gA[p], (char*)As + lOff[p]);
      async16(gB[p], (char*)Bs + lOff[p]);
      gA[p] += 64;
      gB[p] += 64;
    }
    asm volatile("s_waitcnt vmcnt(0)" ::: "memory");
    __syncthreads();
#pragma unroll
    for (int ks = 0; ks < 2; ++ks) {
      bf16x8 af[4], bfv[4];
#pragma unroll
      for (int i = 0; i < 4; ++i) {
        int ra = wrow + i * 16 + l15;
        int g = ks * 4 + quad;
        af[i] = *(const bf16x8*)(As + ra * 64 + ((g ^ (ra & 7)) * 8));
        int rb = wcol + i * 16 + l15;
        bfv[i] = *(const bf16x8*)(Bs + rb * 64 + ((g ^ (rb & 7)) * 8));
      }
#pragma unroll
      for (int i = 0; i < 4; ++i)
#pragma unroll
        for (int j = 0; j < 4; ++j)
          acc[i][j] = __builtin_amdgcn_mfma_f32_16x16x32_bf16(af[i], bfv[j],
                                                              acc[i][j], 0, 0, 0);
    }
    __syncthreads();
  }

  float ks4[4];
#pragma unroll
  for (int j = 0; j < 4; ++j) ks4[j] = kscale[n0 + wcol + j * 16 + l15];

#pragma unroll
  for (int i = 0; i < 4; ++i) {
#pragma unroll
    for (int r = 0; r < 4; ++r) {
      int row = m0 + wrow + i * 16 + quad * 4 + r;
      float qs = rsqrtf(fmaxf(qsum[row], 1e-16f));  // == 1/max(norm,1e-8)
      float best = -1e30f;
      int bidx = 0;
#pragma unroll
      for (int j = 0; j < 4; ++j) {
        int col = n0 + wcol + j * 16 + l15;
        float v = acc[i][j][r] * qs * ks4[j];
        if (v > best) { best = v; bidx = col; }
      }
      unsigned int u = __float_as_uint(best);
      unsigned int ou = (u & 0x80000000u) ? ~u : (u | 0x80000000u);
      unsigned long long pk =
          ((unsigned long long)ou << 32) |
          (unsigned long long)(0xFFFFFFFFu - (unsigned int)bidx);
#pragma unroll
      for (int m = 1; m < 16; m <<= 1) {
        unsigned long long o = (unsigned long long)__shfl_xor((long long)pk, m, 64);
        if (o > pk) pk = o;
      }
      if (l15 == 0) atomicMax(amax + row, pk);
    }
  }
}

// 64x64-tile conf-net GEMM. ZSUM: block (0,0) thread 0 zeroes the cmean
// accumulator (dispatch ordering puts this strictly before conf_head_reduce).
template <int ACT>
__global__ __launch_bounds__(256, 2) void gemm64(
    const bf16* __restrict__ A, const bf16* __restrict__ Bt,
    const bf16* __restrict__ bias, bf16* __restrict__ C,
    float* __restrict__ zsum, int M, int N, int K,
    const int* __restrict__ gate) {
  if (gate && *gate == 0) return;
  if (zsum && blockIdx.x == 0 && blockIdx.y == 0 && threadIdx.x == 0)
    *zsum = 0.f;
  __shared__ __align__(16) bf16 As[64 * 64];
  __shared__ __align__(16) bf16 Bs[64 * 64];

  const int t = threadIdx.x;
  const int lane = t & 63;
  const int wave = t >> 6;
  const int m0 = blockIdx.y * 64;
  const int n0 = blockIdx.x * 64;

  const bf16* gA[2];
  const bf16* gB[2];
  int lOff[2];
#pragma unroll
  for (int p = 0; p < 2; ++p) {
    int c = p * 256 + t;
    int r = c >> 3;
    int g = (c & 7) ^ (r & 7);
    gA[p] = A + (size_t)(m0 + r) * K + g * 8;
    gB[p] = Bt + (size_t)(n0 + r) * K + g * 8;
    lOff[p] = c * 16;
  }

  f32x4 acc[2][2];
#pragma unroll
  for (int i = 0; i < 2; ++i)
#pragma unroll
    for (int j = 0; j < 2; ++j) acc[i][j] = (f32x4){0.f, 0.f, 0.f, 0.f};

  const int wrow = (wave >> 1) * 32;
  const int wcol = (wave & 1) * 32;
  const int l15 = lane & 15;
  const int quad = lane >> 4;

  for (int kt = 0; kt < K; kt += 64) {
#pragma unroll
    for (int p = 0; p < 2; ++p) {
      async16(gA[p], (char*)As + lOff[p]);
      async16(gB[p], (char*)Bs + lOff[p]);
      gA[p] += 64;
      gB[p] += 64;
    }
    asm volatile("s_waitcnt vmcnt(0)" ::: "memory");
    __syncthreads();
#pragma unroll
    for (int ks = 0; ks < 2; ++ks) {
      bf16x8 af[2], bfv[2];
#pragma unroll
      for (int i = 0; i < 2; ++i) {
        int ra = wrow + i * 16 + l15;
        int g = ks * 4 + quad;
        af[i] = *(const bf16x8*)(As + ra * 64 + ((g ^ (ra & 7)) * 8));
        int rb = wcol + i * 16 + l15;
        bfv[i] = *(const bf16x8*)(Bs + rb * 64 + ((g ^ (rb & 7)) * 8));
      }
#pragma unroll
      for (int i = 0; i < 2; ++i)
#pragma unroll
        for (int j = 0; j < 2; ++j)
          acc[i][j] = __builtin_amdgcn_mfma_f32_16x16x32_bf16(af[i], bfv[j],
                                                              acc[i][j], 0, 0, 0);
    }
    __syncthreads();
  }

#pragma unroll
  for (int j = 0; j < 2; ++j) {
    int col = n0 + wcol + j * 16 + l15;
    float bv = bf2f(bias[col]);
#pragma unroll
    for (int i = 0; i < 2; ++i) {
#pragma unroll
      for (int r = 0; r < 4; ++r) {
        int row = m0 + wrow + i * 16 + quad * 4 + r;
        float v = acc[i][j][r] + bv;
        if (ACT == 1) v = gelu_f(v);
        C[(size_t)row * N + col] = f2bf(v);
      }
    }
  }
}

// --- small kernels ---------------------------------------------------------

__global__ void transpose_any(const void* __restrict__ src, bf16* __restrict__ dst,
                              int R, int C, const int* __restrict__ flag) {
  __shared__ bf16 tile[64][65];
  const int isf = *flag;
  int c0 = blockIdx.x * 64, r0 = blockIdx.y * 64;
#pragma unroll 4
  for (int p = 0; p < 16; ++p) {
    int idx = p * 256 + threadIdx.x;
    int r = idx >> 6, c = idx & 63;
    size_t si = (size_t)(r0 + r) * C + (c0 + c);
    tile[r][c] = isf ? f2bf(((const float*)src)[si]) : ((const bf16*)src)[si];
  }
  __syncthreads();
#pragma unroll 4
  for (int p = 0; p < 16; ++p) {
    int idx = p * 256 + threadIdx.x;
    int r = idx >> 6, c = idx & 63;
    dst[(size_t)(c0 + r) * R + (r0 + c)] = tile[c][r];
  }
}

__global__ void key_scale(const bf16* __restrict__ keys, const void* __restrict__ usage,
                          float* __restrict__ kscale, int cols,
                          const int* __restrict__ flag) {
  int row = blockIdx.x;
  const bf16* xr = keys + (size_t)row * cols;
  float s = 0.f;
  for (int i = threadIdx.x * 8; i < cols; i += 256 * 8) {
    union { uint4 u; bf16 h[8]; } u;
    u.u = *(const uint4*)(xr + i);
#pragma unroll
    for (int j = 0; j < 8; ++j) { float f = bf2f(u.h[j]); s += f * f; }
  }
  __shared__ float red[256];
  red[threadIdx.x] = s;
  __syncthreads();
  for (int k = 128; k > 0; k >>= 1) {
    if (threadIdx.x < k) red[threadIdx.x] += red[threadIdx.x + k];
    __syncthreads();
  }
  if (threadIdx.x == 0) {
    float us = *flag ? ((const float*)usage)[row] : bf2f(((const bf16*)usage)[row]);
    kscale[row] = us / fmaxf(sqrtf(red[0]), 1e-8f);
  }
}

// per-row conf head + per-block partial of sum(conf) -> one atomicAdd/block
__global__ void conf_head_reduce(const bf16* __restrict__ h2,
                                 const bf16* __restrict__ w3,
                                 const bf16* __restrict__ b3,
                                 const bf16* __restrict__ slope,
                                 const bf16* __restrict__ cbias,
                                 float* __restrict__ conf,
                                 float* __restrict__ csum,
                                 const int* __restrict__ gate) {
  if (gate && *gate == 0) return;
  int wave = threadIdx.x >> 6, lane = threadIdx.x & 63;
  int row = blockIdx.x * 4 + wave;
  const bf16* hr = h2 + (size_t)row * CH2_DIM;
  float s = bf2f(hr[lane]) * bf2f(w3[lane]) +
            bf2f(hr[lane + 64]) * bf2f(w3[lane + 64]);
  for (int m = 32; m > 0; m >>= 1) s += __shfl_xor(s, m, 64);
  __shared__ float part[4];
  if (lane == 0) {
    float raw = sigmoid_f(s + bf2f(b3[0]));
    float c = sigmoid_f(bf2f(slope[0]) * (raw - 0.5f) + bf2f(cbias[0]));
    conf[row] = c;
    part[wave] = c;
  }
  __syncthreads();
  if (threadIdx.x == 0)
    atomicAdd(csum, part[0] + part[1] + part[2] + part[3]);
}

// ctrl: [0]=adaptive_max_depth, [1]=depth, [2]=stopped, [3..7]=do_compute[d]
__global__ void init_control(const float* __restrict__ csum, int* __restrict__ ctrl) {
  float cf = 1.0f - (*csum / (float)B_DIM);
  int amd = 1 + (int)(cf * 4.0f);  // truncation matches .astype(int32)
  if (amd > 5) amd = 5;
  ctrl[0] = amd;
  ctrl[1] = 0;
  ctrl[2] = 0;
}

// control step + unconditional clear of lookup accumulators (grid B/256)
__global__ void step_control(const float* __restrict__ csum, int* __restrict__ ctrl,
                             int d, unsigned long long* __restrict__ amax,
                             float* __restrict__ qsum, int n) {
  int i = blockIdx.x * 256 + threadIdx.x;
  if (i < n) { amax[i] = 0ull; qsum[i] = 0.f; }
  if (i == 0) {
    int amd = ctrl[0], depth = ctrl[1], stopped = ctrl[2];
    bool brk = ((*csum / (float)B_DIM) >= 0.85f);
    bool active = (!stopped) && (d < amd);
    if (active) depth = d + 1;
    ctrl[3 + d] = (active && !brk) ? 1 : 0;
    if (active && brk) stopped = 1;
    ctrl[1] = depth;
    ctrl[2] = stopped;
  }
}

// in-place: replace S row with mem_values row only when best_sim > 0.9
__global__ void select_mem(const unsigned long long* __restrict__ amax,
                           const void* __restrict__ mv, bf16* __restrict__ S,
                           int Hc, const int* __restrict__ gate,
                           const int* __restrict__ flag) {
  if (*gate == 0) return;
  int b = blockIdx.x;
  unsigned long long pk = amax[b];
  unsigned int ou = (unsigned int)(pk >> 32);
  if (!(ou > 0xBF666666u)) return;  // ordered(0.9f); strict >
  int idx = (int)(0xFFFFFFFFu - (unsigned int)(pk & 0xFFFFFFFFull));
  bf16* dst = S + (size_t)b * Hc;
  if (*flag) {
    const float* src = (const float*)mv + (size_t)idx * Hc;
    for (int i = threadIdx.x; i < Hc; i += 256) dst[i] = f2bf(src[i]);
  } else {
    const uint4* src = (const uint4*)((const bf16*)mv + (size_t)idx * Hc);
    for (int i = threadIdx.x; i < Hc / 8; i += 256) ((uint4*)dst)[i] = src[i];
  }
}

__global__ void emit_state(const bf16* __restrict__ S, void* __restrict__ out,
                           int n, const int* __restrict__ flag) {
  int i = blockIdx.x * 256 + threadIdx.x;
  if (i >= n) return;
  if (*flag) ((float*)out)[i] = bf2f(S[i]);
  else       ((bf16*)out)[i] = S[i];
}

__global__ void write_tail(const float* __restrict__ conf, const int* __restrict__ ctrl,
                           void* __restrict__ out, int bh, int n,
                           const int* __restrict__ flag) {
  int i = blockIdx.x * 256 + threadIdx.x;
  if (i >= n) return;
  if (*flag) {
    ((float*)out)[bh + 1 + i] = conf[i];
    if (i == 0) ((float*)out)[bh] = (float)ctrl[1];
  } else {
    ((bf16*)out)[bh + 1 + i] = f2bf(conf[i]);
    if (i == 0) ((bf16*)out)[bh] = f2bf((float)ctrl[1]);
  }
}

// ---------------------------------------------------------------------------

extern "C" void kernel_launch(void* const* d_in, const int* in_sizes, int n_in,
                              void* d_out, int out_size, void* d_ws, size_t ws_size,
                              hipStream_t stream) {
  const int B = B_DIM, H = H_DIM, H2 = 2 * H_DIM, C1 = CH1_DIM, C2 = CH2_DIM,
            NM = NMEM_DIM;
  const void* x = d_in[0];
  const void* cw1 = d_in[1];
  const void* cb1 = d_in[2];
  const void* cw2 = d_in[3];
  const void* cb2 = d_in[4];
  const void* cw3 = d_in[5];
  const void* cb3 = d_in[6];
  const void* cal_slope = d_in[7];
  const void* cal_bias = d_in[8];
  const void* rw1 = d_in[9];
  const void* rb1 = d_in[10];
  const void* rw2 = d_in[11];
  const void* rb2 = d_in[12];
  const void* mqw = d_in[13];
  const void* mqb = d_in[14];
  const void* mem_keys = d_in[15];
  const void* mem_values = d_in[16];
  const void* mem_usage = d_in[17];

  char* ws = (char*)d_ws;
  size_t off = 0;
  auto alloc = [&](size_t bytes) -> char* {
    char* p = ws + off;
    off = (off + bytes + 255) & ~(size_t)255;
    return p;
  };
  bf16* rw1t = (bf16*)alloc((size_t)H2 * H * 2);
  bf16* rw2t = (bf16*)alloc((size_t)H * H2 * 2);
  bf16* mqwt = (bf16*)alloc((size_t)H * H * 2);
  bf16* cw1t = (bf16*)alloc((size_t)C1 * H * 2);
  bf16* cw2t = (bf16*)alloc((size_t)C2 * C1 * 2);
  bf16* keysb = (bf16*)alloc((size_t)NM * H * 2);
  bf16* S = (bf16*)alloc((size_t)B * H * 2);
  bf16* Hbuf = (bf16*)alloc((size_t)B * H2 * 2);  // q aliases lower half
  bf16* q = Hbuf;
  bf16* h1 = (bf16*)alloc((size_t)B * C1 * 2);
  bf16* h2 = (bf16*)alloc((size_t)B * C2 * 2);
  bf16* rb1b = (bf16*)alloc((size_t)H2 * 2);
  bf16* rb2b = (bf16*)alloc((size_t)H * 2);
  bf16* mqbb = (bf16*)alloc((size_t)H * 2);
  bf16* cb1b = (bf16*)alloc((size_t)C1 * 2);
  bf16* cb2b = (bf16*)alloc((size_t)C2 * 2);
  bf16* cw3b = (bf16*)alloc((size_t)C2 * 2);
  bf16* cb3b = (bf16*)alloc(256);
  bf16* slopeb = (bf16*)alloc(256);
  bf16* cbiasb = (bf16*)alloc(256);
  float* conf = (float*)alloc((size_t)B * 4);
  float* qsum = (float*)alloc((size_t)B * 4);
  float* kscale = (float*)alloc((size_t)NM * 4);
  unsigned long long* amax = (unsigned long long*)alloc((size_t)B * 8);
  float* csum = (float*)alloc(256);
  int* ctrl = (int*)alloc(256);
  int* dflag = (int*)alloc(256);
  (void)ws_size; (void)n_in; (void)in_sizes; (void)out_size;

  dim3 blk(256);

  // --- dtype probe ---
  flag_init<<<1, 1, 0, stream>>>(dflag);
  probe_dtype<<<64, blk, 0, stream>>>(x, dflag);

  // --- ingest to bf16 ---
  ingest<<<(B * H + 255) / 256, blk, 0, stream>>>(x, S, B * H, dflag);
  ingest<<<(NM * H + 255) / 256, blk, 0, stream>>>(mem_keys, keysb, NM * H, dflag);
  SmallJobs sj;
  sj.src[0] = rb1;       sj.dst[0] = rb1b;   sj.n[0] = H2;
  sj.src[1] = rb2;       sj.dst[1] = rb2b;   sj.n[1] = H;
  sj.src[2] = mqb;       sj.dst[2] = mqbb;   sj.n[2] = H;
  sj.src[3] = cb1;       sj.dst[3] = cb1b;   sj.n[3] = C1;
  sj.src[4] = cb2;       sj.dst[4] = cb2b;   sj.n[4] = C2;
  sj.src[5] = cw3;       sj.dst[5] = cw3b;   sj.n[5] = C2;
  sj.src[6] = cb3;       sj.dst[6] = cb3b;   sj.n[6] = 1;
  sj.src[7] = cal_slope; sj.dst[7] = slopeb; sj.n[7] = 1;
  sj.src[8] = cal_bias;  sj.dst[8] = cbiasb; sj.n[8] = 1;
  ingest_small<<<9, blk, 0, stream>>>(sj, dflag);

  // --- weight transposes (B^T form for GEMM) + key scales ---
  transpose_any<<<dim3(H2 / 64, H / 64), blk, 0, stream>>>(rw1, rw1t, H, H2, dflag);
  transpose_any<<<dim3(H / 64, H2 / 64), blk, 0, stream>>>(rw2, rw2t, H2, H, dflag);
  transpose_any<<<dim3(H / 64, H / 64), blk, 0, stream>>>(mqw, mqwt, H, H, dflag);
  transpose_any<<<dim3(C1 / 64, H / 64), blk, 0, stream>>>(cw1, cw1t, H, C1, dflag);
  transpose_any<<<dim3(C2 / 64, C1 / 64), blk, 0, stream>>>(cw2, cw2t, C1, C2, dflag);
  key_scale<<<NM, blk, 0, stream>>>(keysb, mem_usage, kscale, H, dflag);

  auto conf_pipe = [&](const bf16* Sin, const int* gate) {
    gemm64<1><<<dim3(C1 / 64, B / 64), blk, 0, stream>>>(Sin, cw1t, cb1b, h1,
                                                         csum, B, C1, H, gate);
    gemm64<1><<<dim3(C2 / 64, B / 64), blk, 0, stream>>>(h1, cw2t, cb2b, h2,
                                                         nullptr, B, C2, C1, gate);
    conf_head_reduce<<<B / 4, blk, 0, stream>>>(h2, cw3b, cb3b, slopeb, cbiasb,
                                                conf, csum, gate);
  };

  conf_pipe(S, nullptr);
  init_control<<<1, 1, 0, stream>>>(csum, ctrl);

  for (int d = 0; d < 5; ++d) {
    step_control<<<B / 256, blk, 0, stream>>>(csum, ctrl, d, amax, qsum, B);
    const int* gate = ctrl + 3 + d;
    if (d >= 1) {
      gemm_bt<128, 0, 1><<<dim3(H / 128, B / 128), blk, 0, stream>>>(
          S, mqwt, mqbb, q, qsum, B, H, H, gate);
      gemm_sim<<<dim3(NM / 128, B / 128), blk, 0, stream>>>(
          q, keysb, qsum, kscale, amax, B, NM, H, gate);
      select_mem<<<B, blk, 0, stream>>>(amax, mem_values, S, H, gate, dflag);
    }
    gemm_bt<128, 1, 0><<<dim3(H2 / 128, B / 128), blk, 0, stream>>>(
        S, rw1t, rb1b, Hbuf, nullptr, B, H2, H, gate);
    gemm_bt<128, 0, 0><<<dim3(H / 128, B / 128), blk, 0, stream>>>(
        Hbuf, rw2t, rb2b, S, nullptr, B, H, H2, gate);
    conf_pipe(S, gate);
  }

  emit_state<<<(B * H + 255) / 256, blk, 0, stream>>>(S, d_out, B * H, dflag);
  write_tail<<<B / 256, blk, 0, stream>>>(conf, ctrl, d_out, B * H, B, dflag);
}